// Round 1
// baseline (21163.158 us; speedup 1.0000x reference)
//
#include <hip/hip_runtime.h>

// ---------------- problem constants ----------------
#define BATCH 64
#define SLEN  512
#define EDIM  512
#define HDIM  1024
#define NBLK  256
#define ZROWS 16                 // z-rows (gate rows) per WG per layer = 4 gates x 4 h-cols
#define K0    (EDIM + HDIM)      // 1536  (layer0: [x | h0])
#define K1    (2 * HDIM)         // 2048  (layer1: [h0' | h1])
#define ROWB0 (K0 * 2)           // 3072 bytes per LDS weight row (bf16)
#define ROWB1 (K1 * 2)           // 4096

typedef __bf16 bf16x8 __attribute__((ext_vector_type(8)));
typedef float  f32x4  __attribute__((ext_vector_type(4)));

__device__ __forceinline__ float sigm(float x) { return 1.0f / (1.0f + __expf(-x)); }
__device__ __forceinline__ float tanhfast(float x) {
  float e = __expf(-2.0f * __builtin_fabsf(x));
  float r = (1.0f - e) / (1.0f + e);
  return x < 0.0f ? -r : r;
}

// 2-level grid barrier: 16 group counters + 1 master counter + generation flag.
// Release chain: each arrival is ACQ_REL RMW; master store is RELEASE; spinners
// do relaxed spin + one ACQUIRE load (single L2-invalidate per block per barrier).
__device__ __forceinline__ void grid_barrier(unsigned* ctrs, unsigned* gen, unsigned epoch) {
  __syncthreads();   // drains this block's stores (vmcnt before s_barrier)
  if (threadIdx.x == 0) {
    const int grp = blockIdx.x & 15;
    unsigned a = __hip_atomic_fetch_add(&ctrs[grp], 1u, __ATOMIC_ACQ_REL, __HIP_MEMORY_SCOPE_AGENT);
    if (a == 15u) {                       // last of this 16-block group
      __hip_atomic_store(&ctrs[grp], 0u, __ATOMIC_RELAXED, __HIP_MEMORY_SCOPE_AGENT);
      unsigned m = __hip_atomic_fetch_add(&ctrs[16], 1u, __ATOMIC_ACQ_REL, __HIP_MEMORY_SCOPE_AGENT);
      if (m == 15u) {                     // last group: release the generation
        __hip_atomic_store(&ctrs[16], 0u, __ATOMIC_RELAXED, __HIP_MEMORY_SCOPE_AGENT);
        __hip_atomic_store(gen, epoch, __ATOMIC_RELEASE, __HIP_MEMORY_SCOPE_AGENT);
      }
    }
    long tries = 0;
    while (__hip_atomic_load(gen, __ATOMIC_RELAXED, __HIP_MEMORY_SCOPE_AGENT) != epoch) {
      __builtin_amdgcn_s_sleep(1);
      if (++tries > (1L << 24)) break;    // anti-hang safety net; never expected
    }
    (void)__hip_atomic_load(gen, __ATOMIC_ACQUIRE, __HIP_MEMORY_SCOPE_AGENT);
  }
  __syncthreads();
}

// Persistent 2-layer LSTM. One WG per CU; each WG owns h-cols [4*wg, 4*wg+4) of
// BOTH layers. Weights bf16-resident in LDS (XOR-swizzled rows). c-state in
// registers. h exchanged via double-buffered global bf16 + grid barrier.
__global__ __launch_bounds__(256, 1) void lstm_persistent(
    const int* __restrict__ x, const float* __restrict__ emb,
    const float* __restrict__ Wx0, const float* __restrict__ bx0,
    const float* __restrict__ Wh0, const float* __restrict__ bh0,
    const float* __restrict__ Wx1, const float* __restrict__ bx1,
    const float* __restrict__ Wh1, const float* __restrict__ bh1,
    const float* __restrict__ fcw, const float* __restrict__ fcb,
    __bf16* h0buf, __bf16* h1buf, unsigned* ctrs, unsigned* gen,
    float* __restrict__ out)
{
  __shared__ __align__(16) unsigned char W0s[ZROWS * ROWB0];   // 48 KiB
  __shared__ __align__(16) unsigned char W1s[ZROWS * ROWB1];   // 64 KiB
  __shared__ float zbuf[BATCH * ZROWS];                        // 4 KiB
  __shared__ float bias0[ZROWS], bias1[ZROWS];

  const int tid = threadIdx.x;
  const int wg  = blockIdx.x;

  // ---- stage weight slices to LDS as bf16, gate-major rows n = gate*4 + jl ----
  for (int idx = tid; idx < ZROWS * K0; idx += 256) {
    int n = idx / K0, k = idx - n * K0;
    int grow = (n >> 2) * HDIM + wg * 4 + (n & 3);
    float v = (k < EDIM) ? Wx0[grow * EDIM + k] : Wh0[grow * HDIM + (k - EDIM)];
    *(__bf16*)(&W0s[n * ROWB0 + (((unsigned)(k << 1)) ^ (unsigned)((n & 7) << 4))]) = (__bf16)v;
  }
  for (int idx = tid; idx < ZROWS * K1; idx += 256) {
    int n = idx / K1, k = idx - n * K1;
    int grow = (n >> 2) * HDIM + wg * 4 + (n & 3);
    float v = (k < HDIM) ? Wx1[grow * HDIM + k] : Wh1[grow * HDIM + (k - HDIM)];
    *(__bf16*)(&W1s[n * ROWB1 + (((unsigned)(k << 1)) ^ (unsigned)((n & 7) << 4))]) = (__bf16)v;
  }
  if (tid < ZROWS) {
    int grow = (tid >> 2) * HDIM + wg * 4 + (tid & 3);
    bias0[tid] = bx0[grow] + bh0[grow];
    bias1[tid] = bx1[grow] + bh1[grow];
  }
  __syncthreads();

  const int lane = tid & 63, wave = tid >> 6;
  const int mrow = lane & 15;           // A-row (batch) / B-col (z-row) within tile
  const int q    = lane >> 4;           // k-subgroup (8 elems each)
  const int brow = wave * 16 + mrow;    // batch row this lane fetches A for
  const int bg   = tid >> 2, jl = tid & 3;   // gate-phase mapping: thread -> (batch, h-col)
  const int hcol = wg * 4 + jl;
  const unsigned bswz = (unsigned)((mrow & 7) << 4);

  float c0 = 0.0f, c1 = 0.0f;
  unsigned epoch = 0;

  for (int t = 0; t < SLEN; ++t) {
    const int pin = t & 1;
    const __bf16* h0in  = h0buf + pin * (BATCH * HDIM);
    __bf16*       h0out = h0buf + (pin ^ 1) * (BATCH * HDIM);
    const __bf16* h1in  = h1buf + pin * (BATCH * HDIM);
    __bf16*       h1out = h1buf + (pin ^ 1) * (BATCH * HDIM);

    // ================= phase A : layer-0 =================
    {
      f32x4 acc0 = {0.f,0.f,0.f,0.f}, acc1 = {0.f,0.f,0.f,0.f};
      const int tok = x[brow * SLEN + t];
      const float* erow = emb + (size_t)tok * EDIM;
      const unsigned brb = (unsigned)(mrow * ROWB0);
      #pragma unroll 4
      for (int k0 = 0; k0 < EDIM; k0 += 32) {            // x-part, fp32 emb -> bf16
        int ka = k0 + q * 8;
        f32x4 e0 = *(const f32x4*)(erow + ka);
        f32x4 e1 = *(const f32x4*)(erow + ka + 4);
        bf16x8 a = { (__bf16)e0[0], (__bf16)e0[1], (__bf16)e0[2], (__bf16)e0[3],
                     (__bf16)e1[0], (__bf16)e1[1], (__bf16)e1[2], (__bf16)e1[3] };
        bf16x8 bb = *(const bf16x8*)(&W0s[brb + (((unsigned)((k0 << 1) + (q << 4))) ^ bswz)]);
        if (k0 & 32) acc1 = __builtin_amdgcn_mfma_f32_16x16x32_bf16(a, bb, acc1, 0, 0, 0);
        else         acc0 = __builtin_amdgcn_mfma_f32_16x16x32_bf16(a, bb, acc0, 0, 0, 0);
      }
      const __bf16* hr = h0in + brow * HDIM;
      #pragma unroll 4
      for (int k0 = 0; k0 < HDIM; k0 += 32) {            // h0-part
        bf16x8 a  = *(const bf16x8*)(hr + k0 + q * 8);
        bf16x8 bb = *(const bf16x8*)(&W0s[brb + (((unsigned)(((EDIM + k0) << 1) + (q << 4))) ^ bswz)]);
        if (k0 & 32) acc1 = __builtin_amdgcn_mfma_f32_16x16x32_bf16(a, bb, acc1, 0, 0, 0);
        else         acc0 = __builtin_amdgcn_mfma_f32_16x16x32_bf16(a, bb, acc0, 0, 0, 0);
      }
      const int zr = wave * 16 + q * 4;  // C layout: col=lane&15, row=(lane>>4)*4+r  [m89]
      #pragma unroll
      for (int r = 0; r < 4; ++r) zbuf[(zr + r) * ZROWS + mrow] = acc0[r] + acc1[r];
    }
    __syncthreads();
    {  // gates: thread (bg, jl) owns one (batch, h-col) cell; c0 stays in a register
      float zf = zbuf[bg * ZROWS +      jl] + bias0[     jl];
      float zi = zbuf[bg * ZROWS +  4 + jl] + bias0[ 4 + jl];
      float zg = zbuf[bg * ZROWS +  8 + jl] + bias0[ 8 + jl];
      float zo = zbuf[bg * ZROWS + 12 + jl] + bias0[12 + jl];
      float f = sigm(zf), i = sigm(zi), g = tanhfast(zg), o = sigm(zo);
      c0 = f * c0 + i * g;
      h0out[bg * HDIM + hcol] = (__bf16)(o * tanhfast(c0));
    }
    grid_barrier(ctrs, gen, ++epoch);

    // ================= phase B : layer-1 =================
    {
      f32x4 acc0 = {0.f,0.f,0.f,0.f}, acc1 = {0.f,0.f,0.f,0.f};
      const __bf16* ar0 = h0out + brow * HDIM;   // fresh h0'
      const __bf16* ar1 = h1in  + brow * HDIM;   // previous h1
      const unsigned brb = (unsigned)(mrow * ROWB1);
      #pragma unroll 4
      for (int k0 = 0; k0 < HDIM; k0 += 32) {
        bf16x8 a  = *(const bf16x8*)(ar0 + k0 + q * 8);
        bf16x8 bb = *(const bf16x8*)(&W1s[brb + (((unsigned)((k0 << 1) + (q << 4))) ^ bswz)]);
        if (k0 & 32) acc1 = __builtin_amdgcn_mfma_f32_16x16x32_bf16(a, bb, acc1, 0, 0, 0);
        else         acc0 = __builtin_amdgcn_mfma_f32_16x16x32_bf16(a, bb, acc0, 0, 0, 0);
      }
      #pragma unroll 4
      for (int k0 = 0; k0 < HDIM; k0 += 32) {
        bf16x8 a  = *(const bf16x8*)(ar1 + k0 + q * 8);
        bf16x8 bb = *(const bf16x8*)(&W1s[brb + (((unsigned)(((HDIM + k0) << 1) + (q << 4))) ^ bswz)]);
        if (k0 & 32) acc1 = __builtin_amdgcn_mfma_f32_16x16x32_bf16(a, bb, acc1, 0, 0, 0);
        else         acc0 = __builtin_amdgcn_mfma_f32_16x16x32_bf16(a, bb, acc0, 0, 0, 0);
      }
      const int zr = wave * 16 + q * 4;
      #pragma unroll
      for (int r = 0; r < 4; ++r) zbuf[(zr + r) * ZROWS + mrow] = acc0[r] + acc1[r];
    }
    __syncthreads();
    {
      float zf = zbuf[bg * ZROWS +      jl] + bias1[     jl];
      float zi = zbuf[bg * ZROWS +  4 + jl] + bias1[ 4 + jl];
      float zg = zbuf[bg * ZROWS +  8 + jl] + bias1[ 8 + jl];
      float zo = zbuf[bg * ZROWS + 12 + jl] + bias1[12 + jl];
      float f = sigm(zf), i = sigm(zi), g = tanhfast(zg), o = sigm(zo);
      c1 = f * c1 + i * g;
      h1out[bg * HDIM + hcol] = (__bf16)(o * tanhfast(c1));
    }
    grid_barrier(ctrs, gen, ++epoch);
  }

  // ---- final FC: out[b] = sigmoid(h1 . fcw + fcb); final h1 is in parity-0 buf ----
  if (wg == 0) {
    const int q2 = tid & 3, b2 = tid >> 2;
    const __bf16* hr = h1buf + b2 * HDIM + q2 * 256;
    float part = 0.0f;
    for (int k = 0; k < 256; ++k) part += (float)hr[k] * fcw[q2 * 256 + k];
    zbuf[tid] = part;
    __syncthreads();
    if (tid < BATCH) {
      float s = zbuf[tid * 4] + zbuf[tid * 4 + 1] + zbuf[tid * 4 + 2] + zbuf[tid * 4 + 3] + fcb[0];
      out[tid] = 1.0f / (1.0f + __expf(-s));
    }
  }
}

extern "C" void kernel_launch(void* const* d_in, const int* in_sizes, int n_in,
                              void* d_out, int out_size, void* d_ws, size_t ws_size,
                              hipStream_t stream) {
  (void)in_sizes; (void)n_in; (void)out_size; (void)ws_size;
  const int*   x   = (const int*)  d_in[0];
  const float* emb = (const float*)d_in[1];
  const float* Wx0 = (const float*)d_in[2];
  const float* bx0 = (const float*)d_in[3];
  const float* Wh0 = (const float*)d_in[4];
  const float* bh0 = (const float*)d_in[5];
  const float* Wx1 = (const float*)d_in[6];
  const float* bx1 = (const float*)d_in[7];
  const float* Wh1 = (const float*)d_in[8];
  const float* bh1 = (const float*)d_in[9];
  const float* fcw = (const float*)d_in[10];
  const float* fcb = (const float*)d_in[11];
  float* out = (float*)d_out;

  char* ws = (char*)d_ws;
  __bf16*   h0buf = (__bf16*)(ws);              // 2 x [64][1024] bf16 = 262144 B
  __bf16*   h1buf = (__bf16*)(ws + 262144);     // 262144 B
  unsigned* ctrs  = (unsigned*)(ws + 524288);   // 17 counters (pad to 128 B)
  unsigned* genp  = (unsigned*)(ws + 524288 + 128);

  // re-init state every call (harness poisons ws with 0xAA before timing)
  hipMemsetAsync(d_ws, 0, 524288 + 256, stream);
  lstm_persistent<<<NBLK, 256, 0, stream>>>(x, emb, Wx0, bx0, Wh0, bh0,
                                            Wx1, bx1, Wh1, bh1, fcw, fcb,
                                            h0buf, h1buf, ctrs, genp, out);
}

// Round 2
// 11938.622 us; speedup vs baseline: 1.7727x; 1.7727x over previous
//
#include <hip/hip_runtime.h>

// ---------------- problem constants ----------------
#define BATCH 64
#define SLEN  512
#define EDIM  512
#define HDIM  1024
#define NBLK  256
#define HALF  128                // blocks per layer group
#define K0    (EDIM + HDIM)      // 1536  (layer0: [xe | h0])
#define K1    (2 * HDIM)         // 2048  (layer1: [h0' | h1])
#define ROWB  4096               // LDS bytes per weight row (covers K1; K0 uses 3072)
#define ZR    32                 // z-rows per block = 4 gates x 8 h-cols
#define ZSTR  34                 // zbuf row stride (floats), padded vs 32
#define HB    (BATCH * HDIM)     // elems per h slot

// workspace layout
#define WS_CTR   0
#define WS_GEN   128
#define WS_H0    4096
#define WS_H1    (WS_H0 + 2 * HB * 2)          // 4096 + 262144
#define WS_XE    (WS_H1 + 2 * HB * 2)          // 528384
#define XE_BYTES ((size_t)SLEN * BATCH * EDIM * 2)   // 32 MiB

typedef __bf16 bf16x8 __attribute__((ext_vector_type(8)));
typedef float  f32x4  __attribute__((ext_vector_type(4)));

__device__ __forceinline__ float sigm(float x) { return 1.0f / (1.0f + __expf(-x)); }
__device__ __forceinline__ float tanhfast(float x) {
  float e = __expf(-2.0f * __builtin_fabsf(x));
  float r = (1.0f - e) / (1.0f + e);
  return x < 0.0f ? -r : r;
}

// 2-level grid barrier (16 group counters + master + generation flag)
__device__ __forceinline__ void grid_barrier(unsigned* ctrs, unsigned* gen, unsigned epoch) {
  __syncthreads();
  if (threadIdx.x == 0) {
    const int grp = blockIdx.x & 15;
    unsigned a = __hip_atomic_fetch_add(&ctrs[grp], 1u, __ATOMIC_ACQ_REL, __HIP_MEMORY_SCOPE_AGENT);
    if (a == 15u) {
      __hip_atomic_store(&ctrs[grp], 0u, __ATOMIC_RELAXED, __HIP_MEMORY_SCOPE_AGENT);
      unsigned m = __hip_atomic_fetch_add(&ctrs[16], 1u, __ATOMIC_ACQ_REL, __HIP_MEMORY_SCOPE_AGENT);
      if (m == 15u) {
        __hip_atomic_store(&ctrs[16], 0u, __ATOMIC_RELAXED, __HIP_MEMORY_SCOPE_AGENT);
        __hip_atomic_store(gen, epoch, __ATOMIC_RELEASE, __HIP_MEMORY_SCOPE_AGENT);
      }
    }
    long tries = 0;
    while (__hip_atomic_load(gen, __ATOMIC_RELAXED, __HIP_MEMORY_SCOPE_AGENT) != epoch) {
      __builtin_amdgcn_s_sleep(1);
      if (++tries > (1L << 22)) break;   // anti-hang: degrade to wrong answer, never hang
    }
    (void)__hip_atomic_load(gen, __ATOMIC_ACQUIRE, __HIP_MEMORY_SCOPE_AGENT);
  }
  __syncthreads();
}

// ---- xe = bf16(emb[x]) laid out [t][b][e] ----
__global__ void xe_gather(const int* __restrict__ x, const float* __restrict__ emb,
                          __bf16* __restrict__ xe) {
  int g = blockIdx.x * blockDim.x + threadIdx.x;     // one bf16x8 group each
  if (g >= SLEN * BATCH * (EDIM / 8)) return;
  int e8 = g & 63, bt = g >> 6;
  int b = bt & 63, t = bt >> 6;
  int tok = x[b * SLEN + t];
  const float* er = emb + (size_t)tok * EDIM + e8 * 8;
  f32x4 v0 = *(const f32x4*)er, v1 = *(const f32x4*)(er + 4);
  bf16x8 o = { (__bf16)v0[0], (__bf16)v0[1], (__bf16)v0[2], (__bf16)v0[3],
               (__bf16)v1[0], (__bf16)v1[1], (__bf16)v1[2], (__bf16)v1[3] };
  *(bf16x8*)(xe + ((size_t)t * BATCH + b) * EDIM + e8 * 8) = o;
}

// Persistent skewed 2-layer LSTM. Blocks 0..127 = layer0 (step s),
// blocks 128..255 = layer1 (step s-1). 8 h-cols per block, weights in LDS.
__global__ __launch_bounds__(512, 2) void lstm_persistent(
    const int* __restrict__ x, const float* __restrict__ emb,
    const float* __restrict__ Wx0, const float* __restrict__ bx0,
    const float* __restrict__ Wh0, const float* __restrict__ bh0,
    const float* __restrict__ Wx1, const float* __restrict__ bx1,
    const float* __restrict__ Wh1, const float* __restrict__ bh1,
    const float* __restrict__ fcw, const float* __restrict__ fcb,
    const __bf16* __restrict__ xe, int use_xe,
    __bf16* h0buf, __bf16* h1buf, unsigned* ctrs, unsigned* gen,
    float* __restrict__ out)
{
  __shared__ __align__(16) unsigned char Ws[ZR * ROWB];   // 128 KiB
  __shared__ float zbuf[BATCH * ZSTR];                    // 8.5 KiB
  __shared__ float bias[ZR];

  const int tid   = threadIdx.x;
  const int wg    = blockIdx.x;
  const int layer = wg >> 7;       // 0 or 1
  const int sub   = wg & (HALF - 1);

  // ---- stage this block's 32 weight rows (bf16, XOR-swizzled) ----
  if (layer == 0) {
    for (int idx = tid; idx < ZR * K0; idx += 512) {
      int n = idx / K0, k = idx - n * K0;
      int grow = (n >> 3) * HDIM + sub * 8 + (n & 7);
      float v = (k < EDIM) ? Wx0[grow * EDIM + k] : Wh0[grow * HDIM + (k - EDIM)];
      *(__bf16*)(&Ws[n * ROWB + (((unsigned)(k << 1)) ^ (unsigned)((n & 7) << 4))]) = (__bf16)v;
    }
    if (tid < ZR) {
      int grow = (tid >> 3) * HDIM + sub * 8 + (tid & 7);
      bias[tid] = bx0[grow] + bh0[grow];
    }
  } else {
    for (int idx = tid; idx < ZR * K1; idx += 512) {
      int n = idx >> 11, k = idx & (K1 - 1);
      int grow = (n >> 3) * HDIM + sub * 8 + (n & 7);
      float v = (k < HDIM) ? Wx1[grow * HDIM + k] : Wh1[grow * HDIM + (k - HDIM)];
      *(__bf16*)(&Ws[n * ROWB + (((unsigned)(k << 1)) ^ (unsigned)((n & 7) << 4))]) = (__bf16)v;
    }
    if (tid < ZR) {
      int grow = (tid >> 3) * HDIM + sub * 8 + (tid & 7);
      bias[tid] = bx1[grow] + bh1[grow];
    }
  }
  __syncthreads();

  const int lane = tid & 63, wave = tid >> 6;
  const int mrow = lane & 15;            // within-tile row/col
  const int q    = lane >> 4;            // k-subgroup
  const int mt   = wave >> 1, nt = wave & 1;   // 4 batch-tiles x 2 ztile
  const int brow = mt * 16 + mrow;       // batch row for A fragment
  const unsigned brb = (unsigned)((nt * 16 + mrow) * ROWB);
  const unsigned bsw = (unsigned)((mrow & 7) << 4);
  const int bg = tid >> 3, jl = tid & 7; // gate phase: (batch, col-within-8)
  const int hcol = sub * 8 + jl;

  float cst = 0.0f;                      // c-state (one cell per thread)
  unsigned epoch = 0;

#define LDSB(koff) (*(const bf16x8*)(&Ws[brb + (((unsigned)(((koff) << 1) + (q << 4))) ^ bsw)]))

  for (int s = 0; s <= SLEN; ++s) {
    if (layer == 0) {
      if (s < SLEN) {
        const int t = s;
        const __bf16* h0in  = h0buf + ((s + 1) & 1) * HB;   // h0(s-1)
        __bf16*       h0out = h0buf + (s & 1) * HB;         // h0(s)
        f32x4 acc0 = {0.f,0.f,0.f,0.f}, acc1 = {0.f,0.f,0.f,0.f};
        if (use_xe) {
          const __bf16* aX = xe + ((size_t)t * BATCH + brow) * EDIM;
          #pragma unroll 4
          for (int k0 = 0; k0 < EDIM; k0 += 64) {
            bf16x8 a0 = *(const bf16x8*)(aX + k0 + q * 8);
            bf16x8 a1 = *(const bf16x8*)(aX + k0 + 32 + q * 8);
            acc0 = __builtin_amdgcn_mfma_f32_16x16x32_bf16(a0, LDSB(k0), acc0, 0, 0, 0);
            acc1 = __builtin_amdgcn_mfma_f32_16x16x32_bf16(a1, LDSB(k0 + 32), acc1, 0, 0, 0);
          }
        } else {
          const int tok = x[brow * SLEN + t];
          const float* erow = emb + (size_t)tok * EDIM;
          #pragma unroll 4
          for (int k0 = 0; k0 < EDIM; k0 += 32) {
            int ka = k0 + q * 8;
            f32x4 e0 = *(const f32x4*)(erow + ka);
            f32x4 e1 = *(const f32x4*)(erow + ka + 4);
            bf16x8 a = { (__bf16)e0[0], (__bf16)e0[1], (__bf16)e0[2], (__bf16)e0[3],
                         (__bf16)e1[0], (__bf16)e1[1], (__bf16)e1[2], (__bf16)e1[3] };
            if (k0 & 32) acc1 = __builtin_amdgcn_mfma_f32_16x16x32_bf16(a, LDSB(k0), acc1, 0, 0, 0);
            else         acc0 = __builtin_amdgcn_mfma_f32_16x16x32_bf16(a, LDSB(k0), acc0, 0, 0, 0);
          }
        }
        const __bf16* aH = h0in + brow * HDIM;
        #pragma unroll 4
        for (int k0 = 0; k0 < HDIM; k0 += 64) {
          bf16x8 a0 = *(const bf16x8*)(aH + k0 + q * 8);
          bf16x8 a1 = *(const bf16x8*)(aH + k0 + 32 + q * 8);
          acc0 = __builtin_amdgcn_mfma_f32_16x16x32_bf16(a0, LDSB(EDIM + k0), acc0, 0, 0, 0);
          acc1 = __builtin_amdgcn_mfma_f32_16x16x32_bf16(a1, LDSB(EDIM + k0 + 32), acc1, 0, 0, 0);
        }
        const int zb = mt * 16 + q * 4;
        #pragma unroll
        for (int r = 0; r < 4; ++r) zbuf[(zb + r) * ZSTR + nt * 16 + mrow] = acc0[r] + acc1[r];
        __syncthreads();
        {
          float zf = zbuf[bg * ZSTR +      jl] + bias[     jl];
          float zi = zbuf[bg * ZSTR +  8 + jl] + bias[ 8 + jl];
          float zg = zbuf[bg * ZSTR + 16 + jl] + bias[16 + jl];
          float zo = zbuf[bg * ZSTR + 24 + jl] + bias[24 + jl];
          float f = sigm(zf), i = sigm(zi), g = tanhfast(zg), o = sigm(zo);
          cst = f * cst + i * g;
          h0out[bg * HDIM + hcol] = (__bf16)(o * tanhfast(cst));
        }
      }
    } else {
      if (s >= 1) {
        const __bf16* h0in  = h0buf + ((s + 1) & 1) * HB;   // h0(s-1)
        const __bf16* h1in  = h1buf + (s & 1) * HB;         // h1(s-2)
        __bf16*       h1out = h1buf + ((s + 1) & 1) * HB;   // h1(s-1)
        f32x4 acc0 = {0.f,0.f,0.f,0.f}, acc1 = {0.f,0.f,0.f,0.f};
        const __bf16* a0p = h0in + brow * HDIM;
        const __bf16* a1p = h1in + brow * HDIM;
        #pragma unroll 4
        for (int k0 = 0; k0 < HDIM; k0 += 64) {
          bf16x8 a0 = *(const bf16x8*)(a0p + k0 + q * 8);
          bf16x8 a1 = *(const bf16x8*)(a0p + k0 + 32 + q * 8);
          acc0 = __builtin_amdgcn_mfma_f32_16x16x32_bf16(a0, LDSB(k0), acc0, 0, 0, 0);
          acc1 = __builtin_amdgcn_mfma_f32_16x16x32_bf16(a1, LDSB(k0 + 32), acc1, 0, 0, 0);
        }
        #pragma unroll 4
        for (int k0 = 0; k0 < HDIM; k0 += 64) {
          bf16x8 a0 = *(const bf16x8*)(a1p + k0 + q * 8);
          bf16x8 a1 = *(const bf16x8*)(a1p + k0 + 32 + q * 8);
          acc0 = __builtin_amdgcn_mfma_f32_16x16x32_bf16(a0, LDSB(HDIM + k0), acc0, 0, 0, 0);
          acc1 = __builtin_amdgcn_mfma_f32_16x16x32_bf16(a1, LDSB(HDIM + k0 + 32), acc1, 0, 0, 0);
        }
        const int zb = mt * 16 + q * 4;
        #pragma unroll
        for (int r = 0; r < 4; ++r) zbuf[(zb + r) * ZSTR + nt * 16 + mrow] = acc0[r] + acc1[r];
        __syncthreads();
        {
          float zf = zbuf[bg * ZSTR +      jl] + bias[     jl];
          float zi = zbuf[bg * ZSTR +  8 + jl] + bias[ 8 + jl];
          float zg = zbuf[bg * ZSTR + 16 + jl] + bias[16 + jl];
          float zo = zbuf[bg * ZSTR + 24 + jl] + bias[24 + jl];
          float f = sigm(zf), i = sigm(zi), g = tanhfast(zg), o = sigm(zo);
          cst = f * cst + i * g;
          h1out[bg * HDIM + hcol] = (__bf16)(o * tanhfast(cst));
        }
      }
    }
    grid_barrier(ctrs, gen, ++epoch);
  }

  // ---- final FC on first layer-1 block; final h1(511) lives in slot 1 ----
  if (wg == HALF) {
    const __bf16* hf = h1buf + 1 * HB;
    const int q2 = tid & 7, b2 = tid >> 3;
    const __bf16* hr = hf + b2 * HDIM + q2 * 128;
    float part = 0.0f;
    #pragma unroll 8
    for (int k = 0; k < 128; ++k) part += (float)hr[k] * fcw[q2 * 128 + k];
    zbuf[tid] = part;
    __syncthreads();
    if (tid < BATCH) {
      float sacc = fcb[0];
      #pragma unroll
      for (int j = 0; j < 8; ++j) sacc += zbuf[tid * 8 + j];
      out[tid] = 1.0f / (1.0f + __expf(-sacc));
    }
  }
}

extern "C" void kernel_launch(void* const* d_in, const int* in_sizes, int n_in,
                              void* d_out, int out_size, void* d_ws, size_t ws_size,
                              hipStream_t stream) {
  (void)in_sizes; (void)n_in; (void)out_size;
  const int*   x   = (const int*)  d_in[0];
  const float* emb = (const float*)d_in[1];
  const float* Wx0 = (const float*)d_in[2];
  const float* bx0 = (const float*)d_in[3];
  const float* Wh0 = (const float*)d_in[4];
  const float* bh0 = (const float*)d_in[5];
  const float* Wx1 = (const float*)d_in[6];
  const float* bx1 = (const float*)d_in[7];
  const float* Wh1 = (const float*)d_in[8];
  const float* bh1 = (const float*)d_in[9];
  const float* fcw = (const float*)d_in[10];
  const float* fcb = (const float*)d_in[11];
  float* out = (float*)d_out;

  char* ws = (char*)d_ws;
  unsigned* ctrs  = (unsigned*)(ws + WS_CTR);
  unsigned* genp  = (unsigned*)(ws + WS_GEN);
  __bf16*   h0buf = (__bf16*)(ws + WS_H0);
  __bf16*   h1buf = (__bf16*)(ws + WS_H1);
  __bf16*   xe    = (__bf16*)(ws + WS_XE);
  const int use_xe = (ws_size >= (size_t)WS_XE + XE_BYTES) ? 1 : 0;

  hipMemsetAsync(d_ws, 0, WS_XE, stream);   // ctrs + gen + h slots
  if (use_xe) {
    const int groups = SLEN * BATCH * (EDIM / 8);
    xe_gather<<<(groups + 255) / 256, 256, 0, stream>>>(x, emb, xe);
  }
  lstm_persistent<<<NBLK, 512, 0, stream>>>(x, emb, Wx0, bx0, Wh0, bh0,
                                            Wx1, bx1, Wh1, bh1, fcw, fcb,
                                            xe, use_xe, h0buf, h1buf, ctrs, genp, out);
}

// Round 3
// 10020.124 us; speedup vs baseline: 2.1121x; 1.1915x over previous
//
#include <hip/hip_runtime.h>

// ---------------- problem constants ----------------
#define BATCH 64
#define SLEN  512
#define EDIM  512
#define HDIM  1024
#define NBLK  256
#define HALF  128                // blocks per layer group
#define K0    (EDIM + HDIM)      // 1536  layer0 K
#define K1    (2 * HDIM)         // 2048  layer1 K
#define ROWB  4096               // LDS bytes per weight row
#define ZR    32                 // z-rows per block = 4 gates x 8 h-cols
#define ZST   68                 // zbuf batch-row stride (2 nt-partials of 34)
#define HB    (BATCH * HDIM)     // elems per h slot

// workspace layout
#define WS_F0    0
#define WS_F1    512
#define WS_H0    4096
#define WS_H1    (WS_H0 + 4 * HB * 2)       // 4096 + 524288
#define WS_XE    (WS_H1 + 4 * HB * 2)       // 1052672
#define XE_BYTES ((size_t)SLEN * BATCH * EDIM * 2)   // 32 MiB

typedef __bf16 bf16x8 __attribute__((ext_vector_type(8)));
typedef float  f32x4  __attribute__((ext_vector_type(4)));

__device__ __forceinline__ float sigm(float x) { return 1.0f / (1.0f + __expf(-x)); }
__device__ __forceinline__ float tanhfast(float x) {
  float e = __expf(-2.0f * __builtin_fabsf(x));
  float r = (1.0f - e) / (1.0f + e);
  return x < 0.0f ? -r : r;
}

// L2-bypassing 16B load (two relaxed agent-scope u64 atomic loads -> sc0 sc1)
__device__ __forceinline__ bf16x8 ald16(const __bf16* p) {
  union { unsigned long long q[2]; bf16x8 v; } u;
  u.q[0] = __hip_atomic_load((const unsigned long long*)p,       __ATOMIC_RELAXED, __HIP_MEMORY_SCOPE_AGENT);
  u.q[1] = __hip_atomic_load((const unsigned long long*)(p + 4), __ATOMIC_RELAXED, __HIP_MEMORY_SCOPE_AGENT);
  return u.v;
}

// wait until all 128 flags >= target (each wave polls independently; no fences —
// data loads bypass L2 so flag-visibility at L3 is sufficient ordering)
__device__ __forceinline__ void wait_flags(const int* f, int target) {
  if (target <= 0) return;
  const int l = threadIdx.x & 63;
  int tries = 0;
  while (true) {
    int v0 = __hip_atomic_load(f + l,      __ATOMIC_RELAXED, __HIP_MEMORY_SCOPE_AGENT);
    int v1 = __hip_atomic_load(f + l + 64, __ATOMIC_RELAXED, __HIP_MEMORY_SCOPE_AGENT);
    if (__all((v0 >= target) && (v1 >= target))) return;
    __builtin_amdgcn_s_sleep(2);
    if (++tries > (1 << 20)) return;     // anti-hang safety net
  }
}

// ---- xe = bf16(emb[x]) laid out [t][b][e] ----
__global__ void xe_gather(const int* __restrict__ x, const float* __restrict__ emb,
                          __bf16* __restrict__ xe) {
  int g = blockIdx.x * blockDim.x + threadIdx.x;
  if (g >= SLEN * BATCH * (EDIM / 8)) return;
  int e8 = g & 63, bt = g >> 6;
  int b = bt & 63, t = bt >> 6;
  int tok = x[b * SLEN + t];
  const float* er = emb + (size_t)tok * EDIM + e8 * 8;
  f32x4 v0 = *(const f32x4*)er, v1 = *(const f32x4*)(er + 4);
  bf16x8 o = { (__bf16)v0[0], (__bf16)v0[1], (__bf16)v0[2], (__bf16)v0[3],
               (__bf16)v1[0], (__bf16)v1[1], (__bf16)v1[2], (__bf16)v1[3] };
  *(bf16x8*)(xe + ((size_t)t * BATCH + b) * EDIM + e8 * 8) = o;
}

// Persistent skewed 2-layer LSTM, dataflow-flag sync, fence-free h exchange.
__global__ __launch_bounds__(512, 2) void lstm_persistent(
    const int* __restrict__ x, const float* __restrict__ emb,
    const float* __restrict__ Wx0, const float* __restrict__ bx0,
    const float* __restrict__ Wh0, const float* __restrict__ bh0,
    const float* __restrict__ Wx1, const float* __restrict__ bx1,
    const float* __restrict__ Wh1, const float* __restrict__ bh1,
    const __bf16* __restrict__ xe, int use_xe,
    __bf16* h0buf, __bf16* h1buf, int* f0, int* f1)
{
  __shared__ __align__(16) unsigned char Ws[ZR * ROWB];   // 128 KiB
  __shared__ float zbuf[BATCH * ZST];                     // 17 KiB (2 nt-partials)
  __shared__ float bias[ZR];

  const int tid   = threadIdx.x;
  const int wg    = blockIdx.x;
  const int layer = wg >> 7;
  const int sub   = wg & (HALF - 1);

  // ---- stage this block's 32 weight rows (bf16, XOR-swizzled) ----
  if (layer == 0) {
    for (int idx = tid; idx < ZR * K0; idx += 512) {
      int n = idx / K0, k = idx - n * K0;
      int grow = (n >> 3) * HDIM + sub * 8 + (n & 7);
      float v = (k < EDIM) ? Wx0[grow * EDIM + k] : Wh0[grow * HDIM + (k - EDIM)];
      *(__bf16*)(&Ws[n * ROWB + (((unsigned)(k << 1)) ^ (unsigned)((n & 7) << 4))]) = (__bf16)v;
    }
    if (tid < ZR) {
      int grow = (tid >> 3) * HDIM + sub * 8 + (tid & 7);
      bias[tid] = bx0[grow] + bh0[grow];
    }
  } else {
    for (int idx = tid; idx < ZR * K1; idx += 512) {
      int n = idx >> 11, k = idx & (K1 - 1);
      int grow = (n >> 3) * HDIM + sub * 8 + (n & 7);
      float v = (k < HDIM) ? Wx1[grow * HDIM + k] : Wh1[grow * HDIM + (k - HDIM)];
      *(__bf16*)(&Ws[n * ROWB + (((unsigned)(k << 1)) ^ (unsigned)((n & 7) << 4))]) = (__bf16)v;
    }
    if (tid < ZR) {
      int grow = (tid >> 3) * HDIM + sub * 8 + (tid & 7);
      bias[tid] = bx1[grow] + bh1[grow];
    }
  }
  __syncthreads();

  const int lane = tid & 63, wave = tid >> 6;
  const int mrow = lane & 15;
  const int q    = lane >> 4;
  const int mt   = wave >> 1, nt = wave & 1;   // 4 batch-tiles x 2 K-split halves
  const int brow = mt * 16 + mrow;
  const unsigned brb0 = (unsigned)(mrow * ROWB);          // z-cols 0..15
  const unsigned brb1 = (unsigned)((16 + mrow) * ROWB);   // z-cols 16..31
  const unsigned bsw  = (unsigned)((mrow & 7) << 4);
  const int bg = tid >> 3, jl = tid & 7;
  const int hcol = sub * 8 + jl;
  const int zrow = mt * 16 + q * 4;

  float cst = 0.0f;

#define LDSB(brb, koff) (*(const bf16x8*)(&Ws[(brb) + (((unsigned)((((koff) << 1)) + (q << 4))) ^ bsw)]))
#define MFMA(a, b, c) __builtin_amdgcn_mfma_f32_16x16x32_bf16(a, b, c, 0, 0, 0)

  if (layer == 0) {
    for (int s = 0; s < SLEN; ++s) {
      f32x4 acc0 = {0.f,0.f,0.f,0.f}, acc1 = {0.f,0.f,0.f,0.f};
      // --- xe part (no cross-block dep; overlaps the flag wait below) ---
      if (use_xe) {
        const __bf16* aX = xe + ((size_t)s * BATCH + brow) * EDIM;
        #pragma unroll 4
        for (int k0 = nt * 32; k0 < EDIM; k0 += 64) {
          bf16x8 a = *(const bf16x8*)(aX + k0 + q * 8);
          acc0 = MFMA(a, LDSB(brb0, k0), acc0);
          acc1 = MFMA(a, LDSB(brb1, k0), acc1);
        }
      } else {
        const int tok = x[brow * SLEN + s];
        const float* erow = emb + (size_t)tok * EDIM;
        #pragma unroll 4
        for (int k0 = nt * 32; k0 < EDIM; k0 += 64) {
          f32x4 e0 = *(const f32x4*)(erow + k0 + q * 8);
          f32x4 e1 = *(const f32x4*)(erow + k0 + q * 8 + 4);
          bf16x8 a = { (__bf16)e0[0], (__bf16)e0[1], (__bf16)e0[2], (__bf16)e0[3],
                       (__bf16)e1[0], (__bf16)e1[1], (__bf16)e1[2], (__bf16)e1[3] };
          acc0 = MFMA(a, LDSB(brb0, k0), acc0);
          acc1 = MFMA(a, LDSB(brb1, k0), acc1);
        }
      }
      // --- h0(s-1) part ---
      if (s > 0) {
        wait_flags(f0, s);
        const __bf16* hp = h0buf + (size_t)((s - 1) & 3) * HB + brow * HDIM;
        #pragma unroll 4
        for (int k0 = nt * 32; k0 < HDIM; k0 += 64) {
          bf16x8 a = ald16(hp + k0 + q * 8);
          acc0 = MFMA(a, LDSB(brb0, EDIM + k0), acc0);
          acc1 = MFMA(a, LDSB(brb1, EDIM + k0), acc1);
        }
      }
      #pragma unroll
      for (int r = 0; r < 4; ++r) {
        zbuf[(zrow + r) * ZST + nt * 34 + mrow]      = acc0[r];
        zbuf[(zrow + r) * ZST + nt * 34 + 16 + mrow] = acc1[r];
      }
      __syncthreads();
      float zf = zbuf[bg*ZST +      jl] + zbuf[bg*ZST + 34 +      jl] + bias[     jl];
      float zi = zbuf[bg*ZST +  8 + jl] + zbuf[bg*ZST + 34 +  8 + jl] + bias[ 8 + jl];
      float zg = zbuf[bg*ZST + 16 + jl] + zbuf[bg*ZST + 34 + 16 + jl] + bias[16 + jl];
      float zo = zbuf[bg*ZST + 24 + jl] + zbuf[bg*ZST + 34 + 24 + jl] + bias[24 + jl];
      float fg = sigm(zf), ig = sigm(zi), gg = tanhfast(zg), og = sigm(zo);
      cst = fg * cst + ig * gg;
      __bf16 hv = (__bf16)(og * tanhfast(cst));
      // anti-dep: slot s&3 holds h0(s-4); ensure L1 consumed it (f1 >= s-3)
      if (s >= 4) wait_flags(f1, s - 3);
      unsigned short us = __builtin_bit_cast(unsigned short, hv);
      unsigned pw = ((unsigned)us) | (((unsigned)(unsigned short)__shfl_xor((int)us, 1, 64)) << 16);
      if ((tid & 1) == 0)
        __hip_atomic_store((unsigned*)(h0buf + (size_t)(s & 3) * HB + bg * HDIM + hcol),
                           pw, __ATOMIC_RELAXED, __HIP_MEMORY_SCOPE_AGENT);
      __syncthreads();                       // drains all waves' stores (vmcnt 0)
      if (tid == 0)
        __hip_atomic_store(&f0[sub], s + 1, __ATOMIC_RELAXED, __HIP_MEMORY_SCOPE_AGENT);
    }
  } else {
    for (int j = 0; j < SLEN; ++j) {
      f32x4 acc0 = {0.f,0.f,0.f,0.f}, acc1 = {0.f,0.f,0.f,0.f};
      // --- h1(j-1) part first (own-group flags usually already set; overlaps L0) ---
      if (j > 0) {
        wait_flags(f1, j);
        const __bf16* hp = h1buf + (size_t)((j - 1) & 3) * HB + brow * HDIM;
        #pragma unroll 4
        for (int k0 = nt * 32; k0 < HDIM; k0 += 64) {
          bf16x8 a = ald16(hp + k0 + q * 8);
          acc0 = MFMA(a, LDSB(brb0, HDIM + k0), acc0);
          acc1 = MFMA(a, LDSB(brb1, HDIM + k0), acc1);
        }
      }
      // --- h0(j) part ---
      wait_flags(f0, j + 1);
      {
        const __bf16* hp = h0buf + (size_t)(j & 3) * HB + brow * HDIM;
        #pragma unroll 4
        for (int k0 = nt * 32; k0 < HDIM; k0 += 64) {
          bf16x8 a = ald16(hp + k0 + q * 8);
          acc0 = MFMA(a, LDSB(brb0, k0), acc0);
          acc1 = MFMA(a, LDSB(brb1, k0), acc1);
        }
      }
      #pragma unroll
      for (int r = 0; r < 4; ++r) {
        zbuf[(zrow + r) * ZST + nt * 34 + mrow]      = acc0[r];
        zbuf[(zrow + r) * ZST + nt * 34 + 16 + mrow] = acc1[r];
      }
      __syncthreads();
      float zf = zbuf[bg*ZST +      jl] + zbuf[bg*ZST + 34 +      jl] + bias[     jl];
      float zi = zbuf[bg*ZST +  8 + jl] + zbuf[bg*ZST + 34 +  8 + jl] + bias[ 8 + jl];
      float zg = zbuf[bg*ZST + 16 + jl] + zbuf[bg*ZST + 34 + 16 + jl] + bias[16 + jl];
      float zo = zbuf[bg*ZST + 24 + jl] + zbuf[bg*ZST + 34 + 24 + jl] + bias[24 + jl];
      float fg = sigm(zf), ig = sigm(zi), gg = tanhfast(zg), og = sigm(zo);
      cst = fg * cst + ig * gg;
      __bf16 hv = (__bf16)(og * tanhfast(cst));
      unsigned short us = __builtin_bit_cast(unsigned short, hv);
      unsigned pw = ((unsigned)us) | (((unsigned)(unsigned short)__shfl_xor((int)us, 1, 64)) << 16);
      if ((tid & 1) == 0)
        __hip_atomic_store((unsigned*)(h1buf + (size_t)(j & 3) * HB + bg * HDIM + hcol),
                           pw, __ATOMIC_RELAXED, __HIP_MEMORY_SCOPE_AGENT);
      __syncthreads();
      if (tid == 0)
        __hip_atomic_store(&f1[sub], j + 1, __ATOMIC_RELAXED, __HIP_MEMORY_SCOPE_AGENT);
    }
  }
}

// ---- final FC: out[b] = sigmoid(h1(511) . fcw + fcb); h1(511) in slot 3 ----
__global__ void fc_kernel(const __bf16* __restrict__ h1slot,
                          const float* __restrict__ fcw, const float* __restrict__ fcb,
                          float* __restrict__ out) {
  __shared__ float part[512];
  const int tid = threadIdx.x, b = tid >> 3, q2 = tid & 7;
  const __bf16* hr = h1slot + b * HDIM + q2 * 128;
  const float*  wr = fcw + q2 * 128;
  float acc = 0.0f;
  for (int k = 0; k < 128; k += 8) {
    bf16x8 hvv = ald16(hr + k);
    #pragma unroll
    for (int i = 0; i < 8; ++i) acc += (float)hvv[i] * wr[k + i];
  }
  part[tid] = acc;
  __syncthreads();
  if (tid < BATCH) {
    float s = fcb[0];
    #pragma unroll
    for (int i = 0; i < 8; ++i) s += part[tid * 8 + i];
    out[tid] = 1.0f / (1.0f + __expf(-s));
  }
}

extern "C" void kernel_launch(void* const* d_in, const int* in_sizes, int n_in,
                              void* d_out, int out_size, void* d_ws, size_t ws_size,
                              hipStream_t stream) {
  (void)in_sizes; (void)n_in; (void)out_size;
  const int*   x   = (const int*)  d_in[0];
  const float* emb = (const float*)d_in[1];
  const float* Wx0 = (const float*)d_in[2];
  const float* bx0 = (const float*)d_in[3];
  const float* Wh0 = (const float*)d_in[4];
  const float* bh0 = (const float*)d_in[5];
  const float* Wx1 = (const float*)d_in[6];
  const float* bx1 = (const float*)d_in[7];
  const float* Wh1 = (const float*)d_in[8];
  const float* bh1 = (const float*)d_in[9];
  const float* fcw = (const float*)d_in[10];
  const float* fcb = (const float*)d_in[11];
  float* out = (float*)d_out;

  char* ws = (char*)d_ws;
  int*    f0    = (int*)(ws + WS_F0);
  int*    f1    = (int*)(ws + WS_F1);
  __bf16* h0buf = (__bf16*)(ws + WS_H0);
  __bf16* h1buf = (__bf16*)(ws + WS_H1);
  __bf16* xe    = (__bf16*)(ws + WS_XE);
  const int use_xe = (ws_size >= (size_t)WS_XE + XE_BYTES) ? 1 : 0;

  hipMemsetAsync(d_ws, 0, 4096, stream);   // flags only (h slots written before read)
  if (use_xe) {
    const int groups = SLEN * BATCH * (EDIM / 8);
    xe_gather<<<(groups + 255) / 256, 256, 0, stream>>>(x, emb, xe);
  }
  lstm_persistent<<<NBLK, 512, 0, stream>>>(x, emb, Wx0, bx0, Wh0, bh0,
                                            Wx1, bx1, Wh1, bh1,
                                            xe, use_xe, h0buf, h1buf, f0, f1);
  fc_kernel<<<1, 512, 0, stream>>>(h1buf + 3 * (size_t)HB, fcw, fcb, out);
}

// Round 4
// 5468.226 us; speedup vs baseline: 3.8702x; 1.8324x over previous
//
#include <hip/hip_runtime.h>

// ---------------- problem constants ----------------
#define BATCH 64
#define SLEN  512
#define EDIM  512
#define HDIM  1024
#define NBLK  256
#define HALF  128                // blocks per layer group
#define K0    (EDIM + HDIM)      // 1536  layer0 K
#define K1    (2 * HDIM)         // 2048  layer1 K
#define ROWB  4096               // LDS bytes per weight row
#define ZR    32                 // z-rows per block = 4 gates x 8 h-cols
#define ZST   68                 // zbuf batch-row stride (2 nt-partials of 34)
#define HB    (BATCH * HDIM)     // elems per h slot (65536; 128 KiB bf16)
#define RING  8                  // fallback ring depth

#define XE_BYTES ((size_t)SLEN * BATCH * EDIM * 2)      // 32 MiB
#define HBUF_BIG ((size_t)SLEN * HB * 2)                // 64 MiB per layer
#define HBUF_SML ((size_t)RING * HB * 2)                // 1 MiB per layer

typedef __bf16 bf16x8 __attribute__((ext_vector_type(8)));
typedef float  f32x4  __attribute__((ext_vector_type(4)));

__device__ __forceinline__ float sigm(float x) { return 1.0f / (1.0f + __expf(-x)); }
__device__ __forceinline__ float tanhfast(float x) {
  float e = __expf(-2.0f * __builtin_fabsf(x));
  float r = (1.0f - e) / (1.0f + e);
  return x < 0.0f ? -r : r;
}

// L2-bypassing 16B load (fallback path only)
__device__ __forceinline__ bf16x8 ald16(const __bf16* p) {
  union { unsigned long long q[2]; bf16x8 v; } u;
  u.q[0] = __hip_atomic_load((const unsigned long long*)p,       __ATOMIC_RELAXED, __HIP_MEMORY_SCOPE_AGENT);
  u.q[1] = __hip_atomic_load((const unsigned long long*)(p + 4), __ATOMIC_RELAXED, __HIP_MEMORY_SCOPE_AGENT);
  return u.v;
}

template<int BIG>
__device__ __forceinline__ bf16x8 hload(const __bf16* p) {
  if constexpr (BIG) return *(const bf16x8*)p;   // normal load: L2-cached, multicast
  else return ald16(p);                          // ring mode: must bypass (slot reuse)
}

// wait until all 128 flags >= target (per-wave poll; flags always L2-bypassing)
__device__ __forceinline__ void wait_flags(const int* f, int target) {
  if (target <= 0) return;
  const int l = threadIdx.x & 63;
  int tries = 0;
  while (true) {
    int v0 = __hip_atomic_load(f + l,      __ATOMIC_RELAXED, __HIP_MEMORY_SCOPE_AGENT);
    int v1 = __hip_atomic_load(f + l + 64, __ATOMIC_RELAXED, __HIP_MEMORY_SCOPE_AGENT);
    if (__all((v0 >= target) && (v1 >= target))) return;
    __builtin_amdgcn_s_sleep(2);
    if (++tries > (1 << 20)) return;     // anti-hang safety net
  }
}

// ---- xe = bf16(emb[x]) laid out [t][b][e] ----
__global__ void xe_gather(const int* __restrict__ x, const float* __restrict__ emb,
                          __bf16* __restrict__ xe) {
  int g = blockIdx.x * blockDim.x + threadIdx.x;
  if (g >= SLEN * BATCH * (EDIM / 8)) return;
  int e8 = g & 63, bt = g >> 6;
  int b = bt & 63, t = bt >> 6;
  int tok = x[b * SLEN + t];
  const float* er = emb + (size_t)tok * EDIM + e8 * 8;
  f32x4 v0 = *(const f32x4*)er, v1 = *(const f32x4*)(er + 4);
  bf16x8 o = { (__bf16)v0[0], (__bf16)v0[1], (__bf16)v0[2], (__bf16)v0[3],
               (__bf16)v1[0], (__bf16)v1[1], (__bf16)v1[2], (__bf16)v1[3] };
  *(bf16x8*)(xe + ((size_t)t * BATCH + b) * EDIM + e8 * 8) = o;
}

// Persistent skewed 2-layer LSTM. BIG=1: write-once per-step h slots, consumers
// use normal (L2-multicast) loads. BIG=0: 8-slot ring + bypass loads.
template<int BIG>
__global__ __launch_bounds__(512, 2) void lstm_persistent(
    const int* __restrict__ x, const float* __restrict__ emb,
    const float* __restrict__ Wx0, const float* __restrict__ bx0,
    const float* __restrict__ Wh0, const float* __restrict__ bh0,
    const float* __restrict__ Wx1, const float* __restrict__ bx1,
    const float* __restrict__ Wh1, const float* __restrict__ bh1,
    const __bf16* __restrict__ xe, int use_xe,
    __bf16* h0buf, __bf16* h1buf, int* f0, int* f1)
{
  __shared__ __align__(16) unsigned char Ws[ZR * ROWB];   // 128 KiB
  __shared__ float zbuf[BATCH * ZST];                     // 17 KiB
  __shared__ float bias[ZR];

  const int tid   = threadIdx.x;
  const int wg    = blockIdx.x;
  const int layer = wg >> 7;
  const int sub   = wg & (HALF - 1);

  // ---- stage this block's 32 weight rows (bf16, XOR-swizzled) ----
  if (layer == 0) {
    for (int idx = tid; idx < ZR * K0; idx += 512) {
      int n = idx / K0, k = idx - n * K0;
      int grow = (n >> 3) * HDIM + sub * 8 + (n & 7);
      float v = (k < EDIM) ? Wx0[grow * EDIM + k] : Wh0[grow * HDIM + (k - EDIM)];
      *(__bf16*)(&Ws[n * ROWB + (((unsigned)(k << 1)) ^ (unsigned)((n & 7) << 4))]) = (__bf16)v;
    }
    if (tid < ZR) {
      int grow = (tid >> 3) * HDIM + sub * 8 + (tid & 7);
      bias[tid] = bx0[grow] + bh0[grow];
    }
  } else {
    for (int idx = tid; idx < ZR * K1; idx += 512) {
      int n = idx >> 11, k = idx & (K1 - 1);
      int grow = (n >> 3) * HDIM + sub * 8 + (n & 7);
      float v = (k < HDIM) ? Wx1[grow * HDIM + k] : Wh1[grow * HDIM + (k - HDIM)];
      *(__bf16*)(&Ws[n * ROWB + (((unsigned)(k << 1)) ^ (unsigned)((n & 7) << 4))]) = (__bf16)v;
    }
    if (tid < ZR) {
      int grow = (tid >> 3) * HDIM + sub * 8 + (tid & 7);
      bias[tid] = bx1[grow] + bh1[grow];
    }
  }
  __syncthreads();

  const int lane = tid & 63, wave = tid >> 6;
  const int mrow = lane & 15;
  const int q    = lane >> 4;
  const int mt   = wave >> 1, nt = wave & 1;   // 4 batch-tiles x 2 K-split halves
  const int brow = mt * 16 + mrow;
  const unsigned brb0 = (unsigned)(mrow * ROWB);          // z-cols 0..15
  const unsigned brb1 = (unsigned)((16 + mrow) * ROWB);   // z-cols 16..31
  const unsigned bsw  = (unsigned)((mrow & 7) << 4);
  const int bg = tid >> 3, jl = tid & 7;
  const int hcol = sub * 8 + jl;
  const int zrow = mt * 16 + q * 4;

  float cst = 0.0f;

#define SLOT(s)  ((size_t)(BIG ? (s) : ((s) & (RING - 1))) * HB)
#define LDSB(brb, koff) (*(const bf16x8*)(&Ws[(brb) + (((unsigned)((((koff) << 1)) + (q << 4))) ^ bsw)]))
#define MFMA(a, b, c) __builtin_amdgcn_mfma_f32_16x16x32_bf16(a, b, c, 0, 0, 0)

  if (layer == 0) {
    for (int s = 0; s < SLEN; ++s) {
      f32x4 acc0 = {0.f,0.f,0.f,0.f}, acc1 = {0.f,0.f,0.f,0.f};
      // --- xe part (no cross-block dep; overlaps the flag wait below) ---
      if (use_xe) {
        const __bf16* aX = xe + ((size_t)s * BATCH + brow) * EDIM;
        #pragma unroll 4
        for (int k0 = nt * 32; k0 < EDIM; k0 += 64) {
          bf16x8 a = *(const bf16x8*)(aX + k0 + q * 8);
          acc0 = MFMA(a, LDSB(brb0, k0), acc0);
          acc1 = MFMA(a, LDSB(brb1, k0), acc1);
        }
      } else {
        const int tok = x[brow * SLEN + s];
        const float* erow = emb + (size_t)tok * EDIM;
        #pragma unroll 4
        for (int k0 = nt * 32; k0 < EDIM; k0 += 64) {
          f32x4 e0 = *(const f32x4*)(erow + k0 + q * 8);
          f32x4 e1 = *(const f32x4*)(erow + k0 + q * 8 + 4);
          bf16x8 a = { (__bf16)e0[0], (__bf16)e0[1], (__bf16)e0[2], (__bf16)e0[3],
                       (__bf16)e1[0], (__bf16)e1[1], (__bf16)e1[2], (__bf16)e1[3] };
          acc0 = MFMA(a, LDSB(brb0, k0), acc0);
          acc1 = MFMA(a, LDSB(brb1, k0), acc1);
        }
      }
      // --- h0(s-1) part: batch-issue 16 fragment loads, then 32 MFMAs ---
      if (s > 0) {
        wait_flags(f0, s);
        const __bf16* hp = h0buf + SLOT(s - 1) + brow * HDIM + nt * 32 + q * 8;
        bf16x8 af0, af1, af2, af3, af4, af5, af6, af7;
        bf16x8 af8, af9, afa, afb, afc, afd, afe, aff;
        af0 = hload<BIG>(hp + 0*64);  af1 = hload<BIG>(hp + 1*64);
        af2 = hload<BIG>(hp + 2*64);  af3 = hload<BIG>(hp + 3*64);
        af4 = hload<BIG>(hp + 4*64);  af5 = hload<BIG>(hp + 5*64);
        af6 = hload<BIG>(hp + 6*64);  af7 = hload<BIG>(hp + 7*64);
        af8 = hload<BIG>(hp + 8*64);  af9 = hload<BIG>(hp + 9*64);
        afa = hload<BIG>(hp +10*64);  afb = hload<BIG>(hp +11*64);
        afc = hload<BIG>(hp +12*64);  afd = hload<BIG>(hp +13*64);
        afe = hload<BIG>(hp +14*64);  aff = hload<BIG>(hp +15*64);
        const int kb = EDIM + nt * 32;
        acc0 = MFMA(af0, LDSB(brb0, kb+0*64), acc0); acc1 = MFMA(af0, LDSB(brb1, kb+0*64), acc1);
        acc0 = MFMA(af1, LDSB(brb0, kb+1*64), acc0); acc1 = MFMA(af1, LDSB(brb1, kb+1*64), acc1);
        acc0 = MFMA(af2, LDSB(brb0, kb+2*64), acc0); acc1 = MFMA(af2, LDSB(brb1, kb+2*64), acc1);
        acc0 = MFMA(af3, LDSB(brb0, kb+3*64), acc0); acc1 = MFMA(af3, LDSB(brb1, kb+3*64), acc1);
        acc0 = MFMA(af4, LDSB(brb0, kb+4*64), acc0); acc1 = MFMA(af4, LDSB(brb1, kb+4*64), acc1);
        acc0 = MFMA(af5, LDSB(brb0, kb+5*64), acc0); acc1 = MFMA(af5, LDSB(brb1, kb+5*64), acc1);
        acc0 = MFMA(af6, LDSB(brb0, kb+6*64), acc0); acc1 = MFMA(af6, LDSB(brb1, kb+6*64), acc1);
        acc0 = MFMA(af7, LDSB(brb0, kb+7*64), acc0); acc1 = MFMA(af7, LDSB(brb1, kb+7*64), acc1);
        acc0 = MFMA(af8, LDSB(brb0, kb+8*64), acc0); acc1 = MFMA(af8, LDSB(brb1, kb+8*64), acc1);
        acc0 = MFMA(af9, LDSB(brb0, kb+9*64), acc0); acc1 = MFMA(af9, LDSB(brb1, kb+9*64), acc1);
        acc0 = MFMA(afa, LDSB(brb0, kb+10*64), acc0); acc1 = MFMA(afa, LDSB(brb1, kb+10*64), acc1);
        acc0 = MFMA(afb, LDSB(brb0, kb+11*64), acc0); acc1 = MFMA(afb, LDSB(brb1, kb+11*64), acc1);
        acc0 = MFMA(afc, LDSB(brb0, kb+12*64), acc0); acc1 = MFMA(afc, LDSB(brb1, kb+12*64), acc1);
        acc0 = MFMA(afd, LDSB(brb0, kb+13*64), acc0); acc1 = MFMA(afd, LDSB(brb1, kb+13*64), acc1);
        acc0 = MFMA(afe, LDSB(brb0, kb+14*64), acc0); acc1 = MFMA(afe, LDSB(brb1, kb+14*64), acc1);
        acc0 = MFMA(aff, LDSB(brb0, kb+15*64), acc0); acc1 = MFMA(aff, LDSB(brb1, kb+15*64), acc1);
      }
      #pragma unroll
      for (int r = 0; r < 4; ++r) {
        zbuf[(zrow + r) * ZST + nt * 34 + mrow]      = acc0[r];
        zbuf[(zrow + r) * ZST + nt * 34 + 16 + mrow] = acc1[r];
      }
      __syncthreads();
      float zf = zbuf[bg*ZST +      jl] + zbuf[bg*ZST + 34 +      jl] + bias[     jl];
      float zi = zbuf[bg*ZST +  8 + jl] + zbuf[bg*ZST + 34 +  8 + jl] + bias[ 8 + jl];
      float zg = zbuf[bg*ZST + 16 + jl] + zbuf[bg*ZST + 34 + 16 + jl] + bias[16 + jl];
      float zo = zbuf[bg*ZST + 24 + jl] + zbuf[bg*ZST + 34 + 24 + jl] + bias[24 + jl];
      float fg = sigm(zf), ig = sigm(zi), gg = tanhfast(zg), og = sigm(zo);
      cst = fg * cst + ig * gg;
      __bf16 hv = (__bf16)(og * tanhfast(cst));
      if constexpr (!BIG) {   // ring anti-dep: slot reused after RING steps
        if (s >= RING) { wait_flags(f1, s - RING + 2); wait_flags(f0, s - RING + 2); }
      }
      unsigned short us = __builtin_bit_cast(unsigned short, hv);
      unsigned pw = ((unsigned)us) | (((unsigned)(unsigned short)__shfl_xor((int)us, 1, 64)) << 16);
      if ((tid & 1) == 0)
        __hip_atomic_store((unsigned*)(h0buf + SLOT(s) + bg * HDIM + hcol),
                           pw, __ATOMIC_RELAXED, __HIP_MEMORY_SCOPE_AGENT);
      __syncthreads();                       // drains all waves' stores (vmcnt 0)
      if (tid == 0)
        __hip_atomic_store(&f0[sub], s + 1, __ATOMIC_RELAXED, __HIP_MEMORY_SCOPE_AGENT);
    }
  } else {
    for (int j = 0; j < SLEN; ++j) {
      f32x4 acc0 = {0.f,0.f,0.f,0.f}, acc1 = {0.f,0.f,0.f,0.f};
      // --- h1(j-1) part (own-group flags usually already set) ---
      if (j > 0) {
        wait_flags(f1, j);
        const __bf16* hp = h1buf + SLOT(j - 1) + brow * HDIM + nt * 32 + q * 8;
        const int kb = HDIM + nt * 32;
        #pragma unroll
        for (int i = 0; i < 16; ++i) {
          bf16x8 a = hload<BIG>(hp + i * 64);
          acc0 = MFMA(a, LDSB(brb0, kb + i*64), acc0);
          acc1 = MFMA(a, LDSB(brb1, kb + i*64), acc1);
        }
      }
      // --- h0(j) part ---
      wait_flags(f0, j + 1);
      {
        const __bf16* hp = h0buf + SLOT(j) + brow * HDIM + nt * 32 + q * 8;
        const int kb = nt * 32;
        #pragma unroll
        for (int i = 0; i < 16; ++i) {
          bf16x8 a = hload<BIG>(hp + i * 64);
          acc0 = MFMA(a, LDSB(brb0, kb + i*64), acc0);
          acc1 = MFMA(a, LDSB(brb1, kb + i*64), acc1);
        }
      }
      #pragma unroll
      for (int r = 0; r < 4; ++r) {
        zbuf[(zrow + r) * ZST + nt * 34 + mrow]      = acc0[r];
        zbuf[(zrow + r) * ZST + nt * 34 + 16 + mrow] = acc1[r];
      }
      __syncthreads();
      float zf = zbuf[bg*ZST +      jl] + zbuf[bg*ZST + 34 +      jl] + bias[     jl];
      float zi = zbuf[bg*ZST +  8 + jl] + zbuf[bg*ZST + 34 +  8 + jl] + bias[ 8 + jl];
      float zg = zbuf[bg*ZST + 16 + jl] + zbuf[bg*ZST + 34 + 16 + jl] + bias[16 + jl];
      float zo = zbuf[bg*ZST + 24 + jl] + zbuf[bg*ZST + 34 + 24 + jl] + bias[24 + jl];
      float fg = sigm(zf), ig = sigm(zi), gg = tanhfast(zg), og = sigm(zo);
      cst = fg * cst + ig * gg;
      __bf16 hv = (__bf16)(og * tanhfast(cst));
      if constexpr (!BIG) {
        if (j >= RING) wait_flags(f1, j - RING + 2);
      }
      unsigned short us = __builtin_bit_cast(unsigned short, hv);
      unsigned pw = ((unsigned)us) | (((unsigned)(unsigned short)__shfl_xor((int)us, 1, 64)) << 16);
      if ((tid & 1) == 0)
        __hip_atomic_store((unsigned*)(h1buf + SLOT(j) + bg * HDIM + hcol),
                           pw, __ATOMIC_RELAXED, __HIP_MEMORY_SCOPE_AGENT);
      __syncthreads();
      if (tid == 0)
        __hip_atomic_store(&f1[sub], j + 1, __ATOMIC_RELAXED, __HIP_MEMORY_SCOPE_AGENT);
    }
  }
}

// ---- final FC: out[b] = sigmoid(h1(511) . fcw + fcb) ----
__global__ void fc_kernel(const __bf16* __restrict__ h1slot,
                          const float* __restrict__ fcw, const float* __restrict__ fcb,
                          float* __restrict__ out) {
  __shared__ float part[512];
  const int tid = threadIdx.x, b = tid >> 3, q2 = tid & 7;
  const __bf16* hr = h1slot + b * HDIM + q2 * 128;
  const float*  wr = fcw + q2 * 128;
  float acc = 0.0f;
  for (int k = 0; k < 128; k += 8) {
    bf16x8 hvv = *(const bf16x8*)(hr + k);   // fresh dispatch: caches invalidated
    #pragma unroll
    for (int i = 0; i < 8; ++i) acc += (float)hvv[i] * wr[k + i];
  }
  part[tid] = acc;
  __syncthreads();
  if (tid < BATCH) {
    float s = fcb[0];
    #pragma unroll
    for (int i = 0; i < 8; ++i) s += part[tid * 8 + i];
    out[tid] = 1.0f / (1.0f + __expf(-s));
  }
}

extern "C" void kernel_launch(void* const* d_in, const int* in_sizes, int n_in,
                              void* d_out, int out_size, void* d_ws, size_t ws_size,
                              hipStream_t stream) {
  (void)in_sizes; (void)n_in; (void)out_size;
  const int*   x   = (const int*)  d_in[0];
  const float* emb = (const float*)d_in[1];
  const float* Wx0 = (const float*)d_in[2];
  const float* bx0 = (const float*)d_in[3];
  const float* Wh0 = (const float*)d_in[4];
  const float* bh0 = (const float*)d_in[5];
  const float* Wx1 = (const float*)d_in[6];
  const float* bx1 = (const float*)d_in[7];
  const float* Wh1 = (const float*)d_in[8];
  const float* bh1 = (const float*)d_in[9];
  const float* fcw = (const float*)d_in[10];
  const float* fcb = (const float*)d_in[11];
  float* out = (float*)d_out;

  char* ws = (char*)d_ws;
  int* f0 = (int*)(ws);
  int* f1 = (int*)(ws + 512);

  const size_t need_big = 4096 + 2 * HBUF_BIG + XE_BYTES;           // ~160.1 MiB
  const size_t need_sml = 4096 + 2 * HBUF_SML + XE_BYTES;           // ~34.1 MiB
  const int big    = (ws_size >= need_big) ? 1 : 0;
  const size_t hbytes = big ? HBUF_BIG : HBUF_SML;
  __bf16* h0buf = (__bf16*)(ws + 4096);
  __bf16* h1buf = (__bf16*)(ws + 4096 + hbytes);
  __bf16* xe    = (__bf16*)(ws + 4096 + 2 * hbytes);
  const int use_xe = (big || ws_size >= need_sml) ? 1 : 0;

  hipMemsetAsync(d_ws, 0, 4096, stream);   // flags only
  if (use_xe) {
    const int groups = SLEN * BATCH * (EDIM / 8);
    xe_gather<<<(groups + 255) / 256, 256, 0, stream>>>(x, emb, xe);
  }
  if (big) {
    lstm_persistent<1><<<NBLK, 512, 0, stream>>>(x, emb, Wx0, bx0, Wh0, bh0,
                                                 Wx1, bx1, Wh1, bh1,
                                                 xe, use_xe, h0buf, h1buf, f0, f1);
    fc_kernel<<<1, 512, 0, stream>>>(h1buf + (size_t)(SLEN - 1) * HB, fcw, fcb, out);
  } else {
    lstm_persistent<0><<<NBLK, 512, 0, stream>>>(x, emb, Wx0, bx0, Wh0, bh0,
                                                 Wx1, bx1, Wh1, bh1,
                                                 xe, use_xe, h0buf, h1buf, f0, f1);
    fc_kernel<<<1, 512, 0, stream>>>(h1buf + (size_t)((SLEN - 1) & (RING - 1)) * HB, fcw, fcb, out);
  }
}

// Round 5
// 5376.212 us; speedup vs baseline: 3.9364x; 1.0171x over previous
//
#include <hip/hip_runtime.h>

// ---------------- problem constants ----------------
#define BATCH 64
#define SLEN  512
#define EDIM  512
#define HDIM  1024
#define NBLK  256
#define HALF  128                // blocks per layer group
#define K0    (EDIM + HDIM)      // 1536  layer0 K
#define K1    (2 * HDIM)         // 2048  layer1 K
#define ROWB  4096               // LDS bytes per weight row
#define ZR    32                 // z-rows per block = 4 gates x 8 h-cols
#define ZST   68                 // zbuf batch-row stride (2 nt-partials of 34)
#define HB    (BATCH * HDIM)     // elems per h slot (65536; 128 KiB bf16)
#define RING  8                  // fallback ring depth

#define XE_BYTES ((size_t)SLEN * BATCH * EDIM * 2)      // 32 MiB
#define HBUF_BIG ((size_t)SLEN * HB * 2)                // 64 MiB per layer
#define HBUF_SML ((size_t)RING * HB * 2)                // 1 MiB per layer

typedef __bf16 bf16x8 __attribute__((ext_vector_type(8)));
typedef float  f32x4  __attribute__((ext_vector_type(4)));
typedef unsigned u32x4 __attribute__((ext_vector_type(4)));

__device__ __forceinline__ float sigm(float x) { return 1.0f / (1.0f + __expf(-x)); }
__device__ __forceinline__ float tanhfast(float x) {
  float e = __expf(-2.0f * __builtin_fabsf(x));
  float r = (1.0f - e) / (1.0f + e);
  return x < 0.0f ? -r : r;
}

// 16B write-through store (visible at L3 once vmcnt drains; never dirty in L2)
__device__ __forceinline__ void st16_wt(__bf16* p, unsigned d0, unsigned d1,
                                        unsigned d2, unsigned d3) {
  u32x4 v = {d0, d1, d2, d3};
  asm volatile("global_store_dwordx4 %0, %1, off sc0 sc1" :: "v"(p), "v"(v) : "memory");
}

// L2-bypassing 16B load (fallback ring path only)
__device__ __forceinline__ bf16x8 ald16(const __bf16* p) {
  union { unsigned long long q[2]; bf16x8 v; } u;
  u.q[0] = __hip_atomic_load((const unsigned long long*)p,       __ATOMIC_RELAXED, __HIP_MEMORY_SCOPE_AGENT);
  u.q[1] = __hip_atomic_load((const unsigned long long*)(p + 4), __ATOMIC_RELAXED, __HIP_MEMORY_SCOPE_AGENT);
  return u.v;
}

template<int BIG>
__device__ __forceinline__ bf16x8 hload(const __bf16* p) {
  if constexpr (BIG) return *(const bf16x8*)p;   // normal load: L2-cached, multicast
  else return ald16(p);                          // ring mode: must bypass (slot reuse)
}

// Block-level wait: wave 0 polls the 128 global flags (L2-bypassing), then
// releases waves 1-7 via an LDS gate (atomic max; targets may be non-monotonic).
__device__ __forceinline__ void block_wait(const int* f, int target, int* gate) {
  if (target <= 0) return;
  if ((threadIdx.x >> 6) == 0) {
    if (__hip_atomic_load(gate, __ATOMIC_RELAXED, __HIP_MEMORY_SCOPE_WORKGROUP) < target) {
      const int l = threadIdx.x & 63;
      int tries = 0;
      while (true) {
        int v0 = __hip_atomic_load(f + l,      __ATOMIC_RELAXED, __HIP_MEMORY_SCOPE_AGENT);
        int v1 = __hip_atomic_load(f + l + 64, __ATOMIC_RELAXED, __HIP_MEMORY_SCOPE_AGENT);
        if (__all((v0 >= target) && (v1 >= target))) break;
        __builtin_amdgcn_s_sleep(1);
        if (++tries > (1 << 21)) break;   // anti-hang safety net
      }
      if (l == 0)
        __hip_atomic_fetch_max(gate, target, __ATOMIC_RELEASE, __HIP_MEMORY_SCOPE_WORKGROUP);
    }
  } else {
    int tries = 0;
    while (__hip_atomic_load(gate, __ATOMIC_ACQUIRE, __HIP_MEMORY_SCOPE_WORKGROUP) < target) {
      __builtin_amdgcn_s_sleep(1);
      if (++tries > (1 << 21)) break;
    }
  }
}

// ---- xe = bf16(emb[x]) laid out [t][b][e] ----
__global__ void xe_gather(const int* __restrict__ x, const float* __restrict__ emb,
                          __bf16* __restrict__ xe) {
  int g = blockIdx.x * blockDim.x + threadIdx.x;
  if (g >= SLEN * BATCH * (EDIM / 8)) return;
  int e8 = g & 63, bt = g >> 6;
  int b = bt & 63, t = bt >> 6;
  int tok = x[b * SLEN + t];
  const float* er = emb + (size_t)tok * EDIM + e8 * 8;
  f32x4 v0 = *(const f32x4*)er, v1 = *(const f32x4*)(er + 4);
  bf16x8 o = { (__bf16)v0[0], (__bf16)v0[1], (__bf16)v0[2], (__bf16)v0[3],
               (__bf16)v1[0], (__bf16)v1[1], (__bf16)v1[2], (__bf16)v1[3] };
  *(bf16x8*)(xe + ((size_t)t * BATCH + b) * EDIM + e8 * 8) = o;
}

// Persistent skewed 2-layer LSTM. BIG=1: write-once per-step h slots, consumers
// use normal (L2-multicast) loads. BIG=0: 8-slot ring + bypass loads.
template<int BIG>
__global__ __launch_bounds__(512, 2) void lstm_persistent(
    const int* __restrict__ x, const float* __restrict__ emb,
    const float* __restrict__ Wx0, const float* __restrict__ bx0,
    const float* __restrict__ Wh0, const float* __restrict__ bh0,
    const float* __restrict__ Wx1, const float* __restrict__ bx1,
    const float* __restrict__ Wh1, const float* __restrict__ bh1,
    const __bf16* __restrict__ xe, int use_xe,
    __bf16* h0buf, __bf16* h1buf, int* f0, int* f1)
{
  __shared__ __align__(16) unsigned char Ws[ZR * ROWB];   // 128 KiB
  __shared__ float zbuf[BATCH * ZST];                     // 17 KiB
  __shared__ float bias[ZR];
  __shared__ int gateF0, gateF1;

  const int tid   = threadIdx.x;
  const int wg    = blockIdx.x;
  const int layer = wg >> 7;
  const int sub   = wg & (HALF - 1);

  if (tid == 0) { gateF0 = 0; gateF1 = 0; }

  // ---- stage this block's 32 weight rows (bf16, XOR-swizzled) ----
  if (layer == 0) {
    for (int idx = tid; idx < ZR * K0; idx += 512) {
      int n = idx / K0, k = idx - n * K0;
      int grow = (n >> 3) * HDIM + sub * 8 + (n & 7);
      float v = (k < EDIM) ? Wx0[grow * EDIM + k] : Wh0[grow * HDIM + (k - EDIM)];
      *(__bf16*)(&Ws[n * ROWB + (((unsigned)(k << 1)) ^ (unsigned)((n & 7) << 4))]) = (__bf16)v;
    }
    if (tid < ZR) {
      int grow = (tid >> 3) * HDIM + sub * 8 + (tid & 7);
      bias[tid] = bx0[grow] + bh0[grow];
    }
  } else {
    for (int idx = tid; idx < ZR * K1; idx += 512) {
      int n = idx >> 11, k = idx & (K1 - 1);
      int grow = (n >> 3) * HDIM + sub * 8 + (n & 7);
      float v = (k < HDIM) ? Wx1[grow * HDIM + k] : Wh1[grow * HDIM + (k - HDIM)];
      *(__bf16*)(&Ws[n * ROWB + (((unsigned)(k << 1)) ^ (unsigned)((n & 7) << 4))]) = (__bf16)v;
    }
    if (tid < ZR) {
      int grow = (tid >> 3) * HDIM + sub * 8 + (tid & 7);
      bias[tid] = bx1[grow] + bh1[grow];
    }
  }
  __syncthreads();

  const int lane = tid & 63, wave = tid >> 6;
  const int mrow = lane & 15;
  const int q    = lane >> 4;
  const int mt   = wave >> 1, nt = wave & 1;   // 4 batch-tiles x 2 K-split halves
  const int brow = mt * 16 + mrow;
  const unsigned brb0 = (unsigned)(mrow * ROWB);          // z-cols 0..15
  const unsigned brb1 = (unsigned)((16 + mrow) * ROWB);   // z-cols 16..31
  const unsigned bsw  = (unsigned)((mrow & 7) << 4);
  const int bg = tid >> 3, jl = tid & 7;
  const int zrow = mt * 16 + q * 4;

  float cst = 0.0f;

#define SLOT(s)  ((size_t)(BIG ? (s) : ((s) & (RING - 1))) * HB)
#define LDSB(brb, koff) (*(const bf16x8*)(&Ws[(brb) + (((unsigned)((((koff) << 1)) + (q << 4))) ^ bsw)]))
#define MFMA(a, b, c) __builtin_amdgcn_mfma_f32_16x16x32_bf16(a, b, c, 0, 0, 0)

// epilogue: gates -> h value -> packed 16B write-through store (lane jl==0)
#define EPILOGUE(hdst, slotExpr, stepVar)                                         \
  do {                                                                            \
    float zf = zbuf[bg*ZST +      jl] + zbuf[bg*ZST + 34 +      jl] + bias[     jl]; \
    float zi = zbuf[bg*ZST +  8 + jl] + zbuf[bg*ZST + 34 +  8 + jl] + bias[ 8 + jl]; \
    float zg = zbuf[bg*ZST + 16 + jl] + zbuf[bg*ZST + 34 + 16 + jl] + bias[16 + jl]; \
    float zo = zbuf[bg*ZST + 24 + jl] + zbuf[bg*ZST + 34 + 24 + jl] + bias[24 + jl]; \
    float fg = sigm(zf), ig = sigm(zi), gg = tanhfast(zg), og = sigm(zo);         \
    cst = fg * cst + ig * gg;                                                     \
    __bf16 hv = (__bf16)(og * tanhfast(cst));                                     \
    unsigned short us = __builtin_bit_cast(unsigned short, hv);                   \
    unsigned pw = ((unsigned)us) | (((unsigned)(unsigned short)__shfl_xor((int)us, 1, 64)) << 16); \
    unsigned d1 = (unsigned)__shfl_xor((int)pw, 2, 64);                           \
    unsigned d2 = (unsigned)__shfl_xor((int)pw, 4, 64);                           \
    unsigned d3 = (unsigned)__shfl_xor((int)pw, 6, 64);                           \
    if (jl == 0)                                                                  \
      st16_wt(hdst + (slotExpr) + bg * HDIM + sub * 8, pw, d1, d2, d3);           \
    asm volatile("s_waitcnt vmcnt(0)" ::: "memory");                              \
  } while (0)

  if (layer == 0) {
    for (int s = 0; s < SLEN; ++s) {
      f32x4 acc0 = {0.f,0.f,0.f,0.f}, acc1 = {0.f,0.f,0.f,0.f};
      // --- xe part (no cross-block dep; overlaps the flag wait below) ---
      if (use_xe) {
        const __bf16* aX = xe + ((size_t)s * BATCH + brow) * EDIM;
        #pragma unroll 4
        for (int k0 = nt * 32; k0 < EDIM; k0 += 64) {
          bf16x8 a = *(const bf16x8*)(aX + k0 + q * 8);
          acc0 = MFMA(a, LDSB(brb0, k0), acc0);
          acc1 = MFMA(a, LDSB(brb1, k0), acc1);
        }
      } else {
        const int tok = x[brow * SLEN + s];
        const float* erow = emb + (size_t)tok * EDIM;
        #pragma unroll 4
        for (int k0 = nt * 32; k0 < EDIM; k0 += 64) {
          f32x4 e0 = *(const f32x4*)(erow + k0 + q * 8);
          f32x4 e1 = *(const f32x4*)(erow + k0 + q * 8 + 4);
          bf16x8 a = { (__bf16)e0[0], (__bf16)e0[1], (__bf16)e0[2], (__bf16)e0[3],
                       (__bf16)e1[0], (__bf16)e1[1], (__bf16)e1[2], (__bf16)e1[3] };
          acc0 = MFMA(a, LDSB(brb0, k0), acc0);
          acc1 = MFMA(a, LDSB(brb1, k0), acc1);
        }
      }
      // --- h0(s-1) part ---
      if (s > 0) {
        block_wait(f0, s, &gateF0);
        const __bf16* hp = h0buf + SLOT(s - 1) + brow * HDIM + nt * 32 + q * 8;
        const int kb = EDIM + nt * 32;
        #pragma unroll
        for (int i = 0; i < 16; ++i) {
          bf16x8 a = hload<BIG>(hp + i * 64);
          acc0 = MFMA(a, LDSB(brb0, kb + i*64), acc0);
          acc1 = MFMA(a, LDSB(brb1, kb + i*64), acc1);
        }
      }
      #pragma unroll
      for (int r = 0; r < 4; ++r) {
        zbuf[(zrow + r) * ZST + nt * 34 + mrow]      = acc0[r];
        zbuf[(zrow + r) * ZST + nt * 34 + 16 + mrow] = acc1[r];
      }
      __syncthreads();
      if constexpr (!BIG) {   // ring anti-dep: slot reused after RING steps
        if (s >= RING) { block_wait(f1, s - RING + 2, &gateF1); block_wait(f0, s - RING + 2, &gateF0); }
      }
      EPILOGUE(h0buf, SLOT(s), s);
      __syncthreads();                       // all waves' stores drained
      if (tid == 0)
        __hip_atomic_store(&f0[sub], s + 1, __ATOMIC_RELAXED, __HIP_MEMORY_SCOPE_AGENT);
    }
  } else {
    for (int j = 0; j < SLEN; ++j) {
      f32x4 acc0 = {0.f,0.f,0.f,0.f}, acc1 = {0.f,0.f,0.f,0.f};
      // --- h1(j-1) part (own-group flags usually already set) ---
      if (j > 0) {
        block_wait(f1, j, &gateF1);
        const __bf16* hp = h1buf + SLOT(j - 1) + brow * HDIM + nt * 32 + q * 8;
        const int kb = HDIM + nt * 32;
        #pragma unroll
        for (int i = 0; i < 16; ++i) {
          bf16x8 a = hload<BIG>(hp + i * 64);
          acc0 = MFMA(a, LDSB(brb0, kb + i*64), acc0);
          acc1 = MFMA(a, LDSB(brb1, kb + i*64), acc1);
        }
      }
      // --- h0(j) part ---
      block_wait(f0, j + 1, &gateF0);
      {
        const __bf16* hp = h0buf + SLOT(j) + brow * HDIM + nt * 32 + q * 8;
        const int kb = nt * 32;
        #pragma unroll
        for (int i = 0; i < 16; ++i) {
          bf16x8 a = hload<BIG>(hp + i * 64);
          acc0 = MFMA(a, LDSB(brb0, kb + i*64), acc0);
          acc1 = MFMA(a, LDSB(brb1, kb + i*64), acc1);
        }
      }
      #pragma unroll
      for (int r = 0; r < 4; ++r) {
        zbuf[(zrow + r) * ZST + nt * 34 + mrow]      = acc0[r];
        zbuf[(zrow + r) * ZST + nt * 34 + 16 + mrow] = acc1[r];
      }
      __syncthreads();
      if constexpr (!BIG) {
        if (j >= RING) block_wait(f1, j - RING + 2, &gateF1);
      }
      EPILOGUE(h1buf, SLOT(j), j);
      __syncthreads();
      if (tid == 0)
        __hip_atomic_store(&f1[sub], j + 1, __ATOMIC_RELAXED, __HIP_MEMORY_SCOPE_AGENT);
    }
  }
}

// ---- final FC: out[b] = sigmoid(h1(511) . fcw + fcb) ----
__global__ void fc_kernel(const __bf16* __restrict__ h1slot,
                          const float* __restrict__ fcw, const float* __restrict__ fcb,
                          float* __restrict__ out) {
  __shared__ float part[512];
  const int tid = threadIdx.x, b = tid >> 3, q2 = tid & 7;
  const __bf16* hr = h1slot + b * HDIM + q2 * 128;
  const float*  wr = fcw + q2 * 128;
  float acc = 0.0f;
  for (int k = 0; k < 128; k += 8) {
    bf16x8 hvv = *(const bf16x8*)(hr + k);   // fresh dispatch: caches invalidated
    #pragma unroll
    for (int i = 0; i < 8; ++i) acc += (float)hvv[i] * wr[k + i];
  }
  part[tid] = acc;
  __syncthreads();
  if (tid < BATCH) {
    float s = fcb[0];
    #pragma unroll
    for (int i = 0; i < 8; ++i) s += part[tid * 8 + i];
    out[tid] = 1.0f / (1.0f + __expf(-s));
  }
}

extern "C" void kernel_launch(void* const* d_in, const int* in_sizes, int n_in,
                              void* d_out, int out_size, void* d_ws, size_t ws_size,
                              hipStream_t stream) {
  (void)in_sizes; (void)n_in; (void)out_size;
  const int*   x   = (const int*)  d_in[0];
  const float* emb = (const float*)d_in[1];
  const float* Wx0 = (const float*)d_in[2];
  const float* bx0 = (const float*)d_in[3];
  const float* Wh0 = (const float*)d_in[4];
  const float* bh0 = (const float*)d_in[5];
  const float* Wx1 = (const float*)d_in[6];
  const float* bx1 = (const float*)d_in[7];
  const float* Wh1 = (const float*)d_in[8];
  const float* bh1 = (const float*)d_in[9];
  const float* fcw = (const float*)d_in[10];
  const float* fcb = (const float*)d_in[11];
  float* out = (float*)d_out;

  char* ws = (char*)d_ws;
  int* f0 = (int*)(ws);
  int* f1 = (int*)(ws + 512);

  const size_t need_big = 4096 + 2 * HBUF_BIG + XE_BYTES;           // ~160.1 MiB
  const size_t need_sml = 4096 + 2 * HBUF_SML + XE_BYTES;           // ~34.1 MiB
  const int big    = (ws_size >= need_big) ? 1 : 0;
  const size_t hbytes = big ? HBUF_BIG : HBUF_SML;
  __bf16* h0buf = (__bf16*)(ws + 4096);
  __bf16* h1buf = (__bf16*)(ws + 4096 + hbytes);
  __bf16* xe    = (__bf16*)(ws + 4096 + 2 * hbytes);
  const int use_xe = (big || ws_size >= need_sml) ? 1 : 0;

  hipMemsetAsync(d_ws, 0, 4096, stream);   // flags only
  if (use_xe) {
    const int groups = SLEN * BATCH * (EDIM / 8);
    xe_gather<<<(groups + 255) / 256, 256, 0, stream>>>(x, emb, xe);
  }
  if (big) {
    lstm_persistent<1><<<NBLK, 512, 0, stream>>>(x, emb, Wx0, bx0, Wh0, bh0,
                                                 Wx1, bx1, Wh1, bh1,
                                                 xe, use_xe, h0buf, h1buf, f0, f1);
    fc_kernel<<<1, 512, 0, stream>>>(h1buf + (size_t)(SLEN - 1) * HB, fcw, fcb, out);
  } else {
    lstm_persistent<0><<<NBLK, 512, 0, stream>>>(x, emb, Wx0, bx0, Wh0, bh0,
                                                 Wx1, bx1, Wh1, bh1,
                                                 xe, use_xe, h0buf, h1buf, f0, f1);
    fc_kernel<<<1, 512, 0, stream>>>(h1buf + (size_t)((SLEN - 1) & (RING - 1)) * HB, fcw, fcb, out);
  }
}